// Round 5
// baseline (586.066 us; speedup 1.0000x reference)
//
#include <hip/hip_runtime.h>

#define BB 32
#define CC 64
#define C2 32
#define HH 56
#define WW 56
#define HW 3136

// ---------------- lepe: depthwise 7x7 conv + bias + bn -> d_out ----------------
// grid (4, B*C): c is block-uniform -> weights staged once in LDS.
__global__ __launch_bounds__(256) void lepe_k(const float* __restrict__ x,
                                              const float* __restrict__ wt,
                                              const float* __restrict__ b,
                                              const float* __restrict__ s,
                                              const float* __restrict__ bb,
                                              float* __restrict__ out) {
    __shared__ float w_s[49];
    const int bc = blockIdx.y;
    const int c = bc & 63;
    const int tid = threadIdx.x;
    if (tid < 49) w_s[tid] = wt[c * 49 + tid];
    __syncthreads();
    const int qi = blockIdx.x * 256 + tid;             // pixel-quad index, need < 784
    if (qi >= 784) return;
    const int r = qi / 14;
    const int c4 = (qi % 14) * 4;
    const float* xp = x + (long)bc * HW;
    float acc0 = 0.f, acc1 = 0.f, acc2 = 0.f, acc3 = 0.f;
    #pragma unroll
    for (int i = 0; i < 7; ++i) {
        const int y = r + i - 3;
        if ((unsigned)y >= HH) continue;
        const float4* row = reinterpret_cast<const float4*>(xp + y * WW + c4 - 4);
        float4 A = make_float4(0.f, 0.f, 0.f, 0.f);
        float4 Cv = make_float4(0.f, 0.f, 0.f, 0.f);
        if (c4 != 0) A = row[0];
        const float4 Bv = row[1];
        if (c4 != 52) Cv = row[2];
        const float w12[12] = {A.x, A.y, A.z, A.w, Bv.x, Bv.y, Bv.z, Bv.w, Cv.x, Cv.y, Cv.z, Cv.w};
        #pragma unroll
        for (int j = 0; j < 7; ++j) {
            const float wv = w_s[i * 7 + j];
            acc0 = fmaf(w12[j + 1], wv, acc0);
            acc1 = fmaf(w12[j + 2], wv, acc1);
            acc2 = fmaf(w12[j + 3], wv, acc2);
            acc3 = fmaf(w12[j + 4], wv, acc3);
        }
    }
    const float bc_ = b[c], sc = s[c], bbc = bb[c];
    float* op = out + (long)bc * HW + r * WW + c4;
    op[0] = (acc0 + bc_) * sc + bbc;
    op[1] = (acc1 + bc_) * sc + bbc;
    op[2] = (acc2 + bc_) * sc + bbc;
    op[3] = (acc3 + bc_) * sc + bbc;
}

// ---------------- prep: pool(8x8 mean) -> wk matmul+bn -> WK = wp * kg^T ----------------
// One block per (b,g). Output per bg: WK1[c][28] (25 used) then WK2[c][52] (49 used), 640 floats.
__global__ __launch_bounds__(256) void prep_k(const float* __restrict__ x,
                                              const float* __restrict__ wk,
                                              const float* __restrict__ wks,
                                              const float* __restrict__ wkb,
                                              const float* __restrict__ wp_w,
                                              float* __restrict__ WK) {
    __shared__ float p_s[32 * 49];
    __shared__ float kg_s[8 * 49];
    const int b = blockIdx.x >> 2;
    const int g = blockIdx.x & 3;
    const int tid = threadIdx.x;
    for (int idx = tid; idx < 1568; idx += 256) {
        const int i = idx / 49, l = idx % 49;
        const int py = l / 7, px = l % 7;
        const float4* xp4 = reinterpret_cast<const float4*>(
            x + ((long)(b * CC + 32 + i)) * HW + py * 8 * WW + px * 8);
        float4 sA = make_float4(0.f, 0.f, 0.f, 0.f);
        float4 sB = make_float4(0.f, 0.f, 0.f, 0.f);
        #pragma unroll
        for (int y = 0; y < 8; ++y) {
            const float4 a = xp4[y * 14];
            const float4 c = xp4[y * 14 + 1];
            sA.x += a.x; sA.y += a.y; sA.z += a.z; sA.w += a.w;
            sB.x += c.x; sB.y += c.y; sB.z += c.z; sB.w += c.w;
        }
        p_s[idx] = (sA.x + sA.y + sA.z + sA.w + sB.x + sB.y + sB.z + sB.w) * (1.f / 64.f);
    }
    __syncthreads();
    for (int idx = tid; idx < 392; idx += 256) {       // 8 outputs of this group x 49
        const int o8 = idx / 49, l = idx % 49;
        const int o = g * 8 + o8;
        float acc = 0.f;
        #pragma unroll
        for (int i = 0; i < 32; ++i) acc = fmaf(wk[o * 32 + i], p_s[i * 49 + l], acc);
        kg_s[idx] = acc * wks[o] + wkb[o];
    }
    __syncthreads();
    for (int idx = tid; idx < 640; idx += 256) {       // 8 c x 80 slots
        const int c = idx / 80, slot = idx % 80;
        float acc = 0.f;
        int m = -1;
        if (slot < 28) { if (slot < 25) m = slot; }
        else           { if (slot < 77) m = 25 + (slot - 28); }
        if (m >= 0) {
            const float* kp = kg_s + c * 49;
            #pragma unroll
            for (int l = 0; l < 49; ++l) acc = fmaf(wp_w[m * 49 + l], kp[l], acc);
        }
        const long base = (long)blockIdx.x * 640;
        if (slot < 28) WK[base + c * 28 + slot] = acc;
        else           WK[base + 224 + c * 52 + (slot - 28)] = acc;
    }
}

// ---------------- mega: q-proj + 4-group attn/mix + dy matmul + bn + lepe add ----------------
// grid (13, B), 256 threads, one thread per pixel. out64[] accumulators live in registers.
__global__ __launch_bounds__(256) void mega_k(const float* __restrict__ x,
                                              const float* __restrict__ WK,
                                              const float* __restrict__ wq_w,
                                              const float* __restrict__ wq_s,
                                              const float* __restrict__ wq_bb,
                                              const float* __restrict__ wp_b,
                                              const float* __restrict__ rpb1,
                                              const float* __restrict__ rpb2,
                                              const float* __restrict__ dy_w,
                                              const float* __restrict__ dy_s,
                                              const float* __restrict__ dy_bb,
                                              float* __restrict__ out) {
    __shared__ float wqT_s[32 * 32];    // [i][o]
    __shared__ float dyT_s[64 * 64];    // [i][o]
    __shared__ float WK_s[2560];        // [g][c*28+m | 224 + c*52+m]
    __shared__ float rpb1_s[324];       // [g][81]
    __shared__ float rpb2_s[676];       // [g][169]
    __shared__ float wpb1_s[25];
    __shared__ float wpb2_s[49];
    __shared__ float wqbn_s[64];        // [0..31]=s, [32..63]=b
    __shared__ float dybn_s[128];       // [0..63]=s, [64..127]=b
    const int tid = threadIdx.x;
    const int b = blockIdx.y;
    for (int i = tid; i < 1024; i += 256) wqT_s[(i & 31) * 32 + (i >> 5)] = wq_w[i];
    for (int i = tid; i < 4096; i += 256) dyT_s[(i & 63) * 64 + (i >> 6)] = dy_w[i];
    {
        const float* wkp = WK + (long)b * 2560;
        for (int i = tid; i < 2560; i += 256) WK_s[i] = wkp[i];
    }
    for (int i = tid; i < 324; i += 256) rpb1_s[i] = rpb1[i];
    for (int i = tid; i < 676; i += 256) rpb2_s[i] = rpb2[i];
    if (tid < 25) wpb1_s[tid] = wp_b[tid];
    if (tid >= 64 && tid < 113) wpb2_s[tid - 64] = wp_b[25 + tid - 64];
    if (tid < 32) wqbn_s[tid] = wq_s[tid];
    if (tid >= 32 && tid < 64) wqbn_s[tid] = wq_bb[tid - 32];
    if (tid < 64) dybn_s[tid] = dy_s[tid];
    if (tid >= 64 && tid < 128) dybn_s[tid] = dy_bb[tid - 64];
    __syncthreads();
    const int n = blockIdx.x * 256 + tid;
    if (n >= HW) return;

    const int ph = n / WW, pw = n % WW;
    const int yr = HH - 1 - ph, xr = WW - 1 - pw;
    const int rh5 = yr < 2 ? yr : (yr > 53 ? yr - 51 : 2);
    const int rw5 = xr < 2 ? xr : (xr > 53 ? xr - 51 : 2);
    const int rh7 = yr < 3 ? yr : (yr > 52 ? yr - 49 : 3);
    const int rw7 = xr < 3 ? xr : (xr > 52 ? xr - 49 : 3);

    const float* xb = x + (long)b * CC * HW + n;       // pixel-n base, channel stride HW
    float* op = out + (long)b * CC * HW + n;

    float out64[64];
    #pragma unroll
    for (int o = 0; o < 64; ++o) out64[o] = 0.f;

    #pragma unroll 1
    for (int g = 0; g < 4; ++g) {
        // ---- q8 for this group ----
        float q8[8];
        #pragma unroll
        for (int c = 0; c < 8; ++c) q8[c] = 0.f;
        for (int i = 0; i < 32; ++i) {
            const float xv = xb[i * HW];
            #pragma unroll
            for (int c = 0; c < 8; ++c)
                q8[c] = fmaf(wqT_s[i * 32 + g * 8 + c], xv, q8[c]);
        }
        #pragma unroll
        for (int c = 0; c < 8; ++c)
            q8[c] = (q8[c] * wqbn_s[g * 8 + c] + wqbn_s[32 + g * 8 + c]) * 0.25f;

        __builtin_amdgcn_sched_barrier(0);

        // ======== phase 1: 25 weights, 5x5 mix over v0 ========
        {
            const float* wk1 = WK_s + g * 640;
            float w1[25];
            #pragma unroll
            for (int m = 0; m < 25; ++m) w1[m] = wpb1_s[m];
            #pragma unroll
            for (int c = 0; c < 8; ++c) {
                const float qv = q8[c];
                #pragma unroll
                for (int m = 0; m < 25; ++m) w1[m] = fmaf(qv, wk1[c * 28 + m], w1[m]);
            }
            const float* rp = rpb1_s + g * 81;
            #pragma unroll
            for (int i = 0; i < 5; ++i)
                #pragma unroll
                for (int j = 0; j < 5; ++j)
                    w1[i * 5 + j] += rp[(rh5 + i) * 9 + (rw5 + j)];
            float mx = -1e30f;
            #pragma unroll
            for (int m = 0; m < 25; ++m) mx = fmaxf(mx, w1[m]);
            float sm = 0.f;
            #pragma unroll
            for (int m = 0; m < 25; ++m) { w1[m] = __expf(w1[m] - mx); sm += w1[m]; }
            const float r = 1.f / sm;
            #pragma unroll
            for (int m = 0; m < 25; ++m) w1[m] *= r;

            const float* vb = xb + (long)(g * 8) * HW;
            float acc[8];
            #pragma unroll
            for (int ch = 0; ch < 8; ++ch) acc[ch] = 0.f;
            #pragma unroll
            for (int i = 0; i < 5; ++i) {
                const int y = ph + i - 2;
                if ((unsigned)y >= HH) continue;
                #pragma unroll
                for (int j = 0; j < 5; ++j) {
                    const int xx = pw + j - 2;
                    if ((unsigned)xx >= WW) continue;
                    const int off = (i - 2) * WW + (j - 2);
                    const float wv = w1[i * 5 + j];
                    #pragma unroll
                    for (int ch = 0; ch < 8; ++ch)
                        acc[ch] = fmaf(wv, vb[ch * HW + off], acc[ch]);
                }
            }
            #pragma unroll
            for (int c = 0; c < 8; ++c) {
                const float mv = acc[c];
                const float* dr = dyT_s + (g * 8 + c) * 64;
                #pragma unroll
                for (int o = 0; o < 64; ++o) out64[o] = fmaf(dr[o], mv, out64[o]);
            }
        }

        __builtin_amdgcn_sched_barrier(0);

        // ======== phase 2: 49 weights, 7x7 mix over v1 ========
        {
            const float* wk2 = WK_s + g * 640 + 224;
            float w2[49];
            #pragma unroll
            for (int m = 0; m < 49; ++m) w2[m] = wpb2_s[m];
            #pragma unroll
            for (int c = 0; c < 8; ++c) {
                const float qv = q8[c];
                #pragma unroll
                for (int m = 0; m < 49; ++m) w2[m] = fmaf(qv, wk2[c * 52 + m], w2[m]);
            }
            const float* rp = rpb2_s + g * 169;
            #pragma unroll
            for (int i = 0; i < 7; ++i)
                #pragma unroll
                for (int j = 0; j < 7; ++j)
                    w2[i * 7 + j] += rp[(rh7 + i) * 13 + (rw7 + j)];
            float mx = -1e30f;
            #pragma unroll
            for (int m = 0; m < 49; ++m) mx = fmaxf(mx, w2[m]);
            float sm = 0.f;
            #pragma unroll
            for (int m = 0; m < 49; ++m) { w2[m] = __expf(w2[m] - mx); sm += w2[m]; }
            const float r = 1.f / sm;
            #pragma unroll
            for (int m = 0; m < 49; ++m) w2[m] *= r;

            const float* vb = xb + (long)(32 + g * 8) * HW;
            float acc[8];
            #pragma unroll
            for (int ch = 0; ch < 8; ++ch) acc[ch] = 0.f;
            #pragma unroll
            for (int i = 0; i < 7; ++i) {
                const int y = ph + i - 3;
                if ((unsigned)y >= HH) continue;
                #pragma unroll
                for (int j = 0; j < 7; ++j) {
                    const int xx = pw + j - 3;
                    if ((unsigned)xx >= WW) continue;
                    const int off = (i - 3) * WW + (j - 3);
                    const float wv = w2[i * 7 + j];
                    #pragma unroll
                    for (int ch = 0; ch < 8; ++ch)
                        acc[ch] = fmaf(wv, vb[ch * HW + off], acc[ch]);
                }
            }
            #pragma unroll
            for (int c = 0; c < 8; ++c) {
                const float mv = acc[c];
                const float* dr = dyT_s + (32 + g * 8 + c) * 64;
                #pragma unroll
                for (int o = 0; o < 64; ++o) out64[o] = fmaf(dr[o], mv, out64[o]);
            }
        }

        __builtin_amdgcn_sched_barrier(0);
    }

    // ---- epilogue: bn + add lepe (already in out) ----
    #pragma unroll
    for (int o = 0; o < 64; ++o)
        op[o * HW] = fmaf(out64[o], dybn_s[o], dybn_s[64 + o]) + op[o * HW];
}

extern "C" void kernel_launch(void* const* d_in, const int* in_sizes, int n_in,
                              void* d_out, int out_size, void* d_ws, size_t ws_size,
                              hipStream_t stream) {
    const float* x       = (const float*)d_in[0];
    const float* lepe_w  = (const float*)d_in[1];
    const float* lepe_b  = (const float*)d_in[2];
    const float* lepe_s  = (const float*)d_in[3];
    const float* lepe_bb = (const float*)d_in[4];
    const float* wq_w    = (const float*)d_in[5];
    const float* wq_s    = (const float*)d_in[6];
    const float* wq_bb   = (const float*)d_in[7];
    const float* wk_w    = (const float*)d_in[8];
    const float* wk_s    = (const float*)d_in[9];
    const float* wk_bb   = (const float*)d_in[10];
    const float* wp_w    = (const float*)d_in[11];
    const float* wp_b    = (const float*)d_in[12];
    const float* rpb1    = (const float*)d_in[13];
    const float* rpb2    = (const float*)d_in[14];
    const float* dy_w    = (const float*)d_in[15];
    const float* dy_s    = (const float*)d_in[16];
    const float* dy_bb   = (const float*)d_in[17];
    float* out = (float*)d_out;

    float* WK_ws = (float*)d_ws;                      // 128*640 floats

    lepe_k<<<dim3(4, BB * CC), 256, 0, stream>>>(x, lepe_w, lepe_b, lepe_s, lepe_bb, out);
    prep_k<<<dim3(BB * 4), 256, 0, stream>>>(x, wk_w, wk_s, wk_bb, wp_w, WK_ws);
    mega_k<<<dim3(13, BB), 256, 0, stream>>>(x, WK_ws, wq_w, wq_s, wq_bb, wp_b,
                                             rpb1, rpb2, dy_w, dy_s, dy_bb, out);
}

// Round 6
// 256.052 us; speedup vs baseline: 2.2889x; 2.2889x over previous
//
#include <hip/hip_runtime.h>

#define BB 32
#define CC 64
#define C2 32
#define HH 56
#define WW 56
#define HW 3136

// ---------------- lepe: depthwise 7x7 conv + bias + bn -> d_out ----------------
// grid (4, B*C): c is block-uniform -> weights staged once in LDS.
__global__ __launch_bounds__(256) void lepe_k(const float* __restrict__ x,
                                              const float* __restrict__ wt,
                                              const float* __restrict__ b,
                                              const float* __restrict__ s,
                                              const float* __restrict__ bb,
                                              float* __restrict__ out) {
    __shared__ float w_s[49];
    const int bc = blockIdx.y;
    const int c = bc & 63;
    const int tid = threadIdx.x;
    if (tid < 49) w_s[tid] = wt[c * 49 + tid];
    __syncthreads();
    const int qi = blockIdx.x * 256 + tid;             // pixel-quad index, need < 784
    if (qi >= 784) return;
    const int r = qi / 14;
    const int c4 = (qi % 14) * 4;
    const float* xp = x + (long)bc * HW;
    float acc0 = 0.f, acc1 = 0.f, acc2 = 0.f, acc3 = 0.f;
    #pragma unroll
    for (int i = 0; i < 7; ++i) {
        const int y = r + i - 3;
        if ((unsigned)y >= HH) continue;
        const float4* row = reinterpret_cast<const float4*>(xp + y * WW + c4 - 4);
        float4 A = make_float4(0.f, 0.f, 0.f, 0.f);
        float4 Cv = make_float4(0.f, 0.f, 0.f, 0.f);
        if (c4 != 0) A = row[0];
        const float4 Bv = row[1];
        if (c4 != 52) Cv = row[2];
        const float w12[12] = {A.x, A.y, A.z, A.w, Bv.x, Bv.y, Bv.z, Bv.w, Cv.x, Cv.y, Cv.z, Cv.w};
        #pragma unroll
        for (int j = 0; j < 7; ++j) {
            const float wv = w_s[i * 7 + j];
            acc0 = fmaf(w12[j + 1], wv, acc0);
            acc1 = fmaf(w12[j + 2], wv, acc1);
            acc2 = fmaf(w12[j + 3], wv, acc2);
            acc3 = fmaf(w12[j + 4], wv, acc3);
        }
    }
    const float bc_ = b[c], sc = s[c], bbc = bb[c];
    float* op = out + (long)bc * HW + r * WW + c4;
    op[0] = (acc0 + bc_) * sc + bbc;
    op[1] = (acc1 + bc_) * sc + bbc;
    op[2] = (acc2 + bc_) * sc + bbc;
    op[3] = (acc3 + bc_) * sc + bbc;
}

// ---------------- prep: pool(8x8 mean) -> wk matmul+bn -> WK = wp * kg^T ----------------
// One block per (b,g). Output per bg: WK1[c][28] (25 used) then WK2[c][52] (49 used), 640 floats.
__global__ __launch_bounds__(256) void prep_k(const float* __restrict__ x,
                                              const float* __restrict__ wk,
                                              const float* __restrict__ wks,
                                              const float* __restrict__ wkb,
                                              const float* __restrict__ wp_w,
                                              float* __restrict__ WK) {
    __shared__ float p_s[32 * 49];
    __shared__ float kg_s[8 * 49];
    const int b = blockIdx.x >> 2;
    const int g = blockIdx.x & 3;
    const int tid = threadIdx.x;
    for (int idx = tid; idx < 1568; idx += 256) {
        const int i = idx / 49, l = idx % 49;
        const int py = l / 7, px = l % 7;
        const float4* xp4 = reinterpret_cast<const float4*>(
            x + ((long)(b * CC + 32 + i)) * HW + py * 8 * WW + px * 8);
        float4 sA = make_float4(0.f, 0.f, 0.f, 0.f);
        float4 sB = make_float4(0.f, 0.f, 0.f, 0.f);
        #pragma unroll
        for (int y = 0; y < 8; ++y) {
            const float4 a = xp4[y * 14];
            const float4 c = xp4[y * 14 + 1];
            sA.x += a.x; sA.y += a.y; sA.z += a.z; sA.w += a.w;
            sB.x += c.x; sB.y += c.y; sB.z += c.z; sB.w += c.w;
        }
        p_s[idx] = (sA.x + sA.y + sA.z + sA.w + sB.x + sB.y + sB.z + sB.w) * (1.f / 64.f);
    }
    __syncthreads();
    for (int idx = tid; idx < 392; idx += 256) {       // 8 outputs of this group x 49
        const int o8 = idx / 49, l = idx % 49;
        const int o = g * 8 + o8;
        float acc = 0.f;
        #pragma unroll
        for (int i = 0; i < 32; ++i) acc = fmaf(wk[o * 32 + i], p_s[i * 49 + l], acc);
        kg_s[idx] = acc * wks[o] + wkb[o];
    }
    __syncthreads();
    for (int idx = tid; idx < 640; idx += 256) {       // 8 c x 80 slots
        const int c = idx / 80, slot = idx % 80;
        float acc = 0.f;
        int m = -1;
        if (slot < 28) { if (slot < 25) m = slot; }
        else           { if (slot < 77) m = 25 + (slot - 28); }
        if (m >= 0) {
            const float* kp = kg_s + c * 49;
            #pragma unroll
            for (int l = 0; l < 49; ++l) acc = fmaf(wp_w[m * 49 + l], kp[l], acc);
        }
        const long base = (long)blockIdx.x * 640;
        if (slot < 28) WK[base + c * 28 + slot] = acc;
        else           WK[base + 224 + c * 52 + (slot - 28)] = acc;
    }
}

// ---------------- fused q-proj + attention (wm via WK -> +rpb -> softmax) + dyn_mix ----------------
// Per (b,g) block. q8 computed inline (no q workspace). Two phases, 8-acc ILP gathers.
__global__ __launch_bounds__(256) void attnmix_k(const float* __restrict__ x,
                                                 const float* __restrict__ WK,
                                                 const float* __restrict__ wq_w,
                                                 const float* __restrict__ wq_s,
                                                 const float* __restrict__ wq_bb,
                                                 const float* __restrict__ wp_b,
                                                 const float* __restrict__ rpb1,
                                                 const float* __restrict__ rpb2,
                                                 float* __restrict__ mix) {
    __shared__ float WK1_s[8 * 28];     // [c][28], pad zeroed
    __shared__ float WK2_s[8 * 52];     // [c][52], pad zeroed
    __shared__ float wqT_s[32 * 8];     // [i][c] = wq_w[(g*8+c)*32+i]
    __shared__ float wpb1_s[25];
    __shared__ float wpb2_s[49];
    __shared__ float rpb1_s[81];
    __shared__ float rpb2_s[169];
    __shared__ float wqbn_s[16];        // [0..7]=s, [8..15]=b
    const int tid = threadIdx.x;
    const int bg = blockIdx.y;
    const int g = bg & 3, b = bg >> 2;
    {
        const float* wkp = WK + (long)bg * 640;
        for (int i = tid; i < 224; i += 256) WK1_s[i] = wkp[i];
        for (int i = tid; i < 416; i += 256) WK2_s[i] = wkp[224 + i];
    }
    if (tid < 256) {                    // wqT: i = tid>>3, c = tid&7
        const int i = tid >> 3, c = tid & 7;
        wqT_s[tid] = wq_w[(g * 8 + c) * 32 + i];
    }
    if (tid < 25) wpb1_s[tid] = wp_b[tid];
    if (tid >= 32 && tid < 81) wpb2_s[tid - 32] = wp_b[25 + tid - 32];
    if (tid < 81) rpb1_s[tid] = rpb1[g * 81 + tid];
    if (tid < 169) rpb2_s[tid] = rpb2[g * 169 + tid];
    if (tid >= 192 && tid < 200) wqbn_s[tid - 192] = wq_s[g * 8 + tid - 192];
    if (tid >= 200 && tid < 208) wqbn_s[8 + tid - 200] = wq_bb[g * 8 + tid - 200];
    __syncthreads();
    const int n = blockIdx.x * 256 + tid;
    if (n >= HW) return;

    const int ph = n / WW, pw = n % WW;
    const int yr = HH - 1 - ph, xr = WW - 1 - pw;

    const float* xb = x + (long)b * CC * HW + n;       // pixel-n base, channel stride HW

    // ---- q8 inline: q = wq . x[0..32) , bn, *SCALE ----
    float q8[8];
    #pragma unroll
    for (int c = 0; c < 8; ++c) q8[c] = 0.f;
    for (int i = 0; i < 32; ++i) {
        const float xv = xb[i * HW];
        #pragma unroll
        for (int c = 0; c < 8; ++c) q8[c] = fmaf(wqT_s[i * 8 + c], xv, q8[c]);
    }
    #pragma unroll
    for (int c = 0; c < 8; ++c)
        q8[c] = (q8[c] * wqbn_s[c] + wqbn_s[8 + c]) * 0.25f;

    __builtin_amdgcn_sched_barrier(0);

    // ======== phase 1: 25 weights, 5x5 mix over v0 ========
    {
        float w1[25];
        #pragma unroll
        for (int m = 0; m < 25; ++m) w1[m] = wpb1_s[m];
        #pragma unroll
        for (int c = 0; c < 8; ++c) {
            const float qv = q8[c];
            #pragma unroll
            for (int m = 0; m < 25; ++m) w1[m] = fmaf(qv, WK1_s[c * 28 + m], w1[m]);
        }
        const int rh5 = yr < 2 ? yr : (yr > 53 ? yr - 51 : 2);
        const int rw5 = xr < 2 ? xr : (xr > 53 ? xr - 51 : 2);
        #pragma unroll
        for (int i = 0; i < 5; ++i)
            #pragma unroll
            for (int j = 0; j < 5; ++j)
                w1[i * 5 + j] += rpb1_s[(rh5 + i) * 9 + (rw5 + j)];
        float mx = -1e30f;
        #pragma unroll
        for (int m = 0; m < 25; ++m) mx = fmaxf(mx, w1[m]);
        float sm = 0.f;
        #pragma unroll
        for (int m = 0; m < 25; ++m) { w1[m] = __expf(w1[m] - mx); sm += w1[m]; }
        const float r = 1.f / sm;
        #pragma unroll
        for (int m = 0; m < 25; ++m) w1[m] *= r;

        const float* vb = xb + (long)(g * 8) * HW;
        float acc[8];
        #pragma unroll
        for (int ch = 0; ch < 8; ++ch) acc[ch] = 0.f;
        #pragma unroll
        for (int i = 0; i < 5; ++i) {
            const int y = ph + i - 2;
            if ((unsigned)y >= HH) continue;
            #pragma unroll
            for (int j = 0; j < 5; ++j) {
                const int xx = pw + j - 2;
                if ((unsigned)xx >= WW) continue;
                const int off = (i - 2) * WW + (j - 2);
                const float wv = w1[i * 5 + j];
                #pragma unroll
                for (int ch = 0; ch < 8; ++ch)
                    acc[ch] = fmaf(wv, vb[ch * HW + off], acc[ch]);
            }
        }
        float* m0 = mix + ((long)b * CC + g * 8) * HW + n;
        #pragma unroll
        for (int ch = 0; ch < 8; ++ch) m0[ch * HW] = acc[ch];
    }

    __builtin_amdgcn_sched_barrier(0);   // keep phases from merging (register pressure)

    // ======== phase 2: 49 weights, 7x7 mix over v1 ========
    {
        float w2[49];
        #pragma unroll
        for (int m = 0; m < 49; ++m) w2[m] = wpb2_s[m];
        #pragma unroll
        for (int c = 0; c < 8; ++c) {
            const float qv = q8[c];
            #pragma unroll
            for (int m = 0; m < 49; ++m) w2[m] = fmaf(qv, WK2_s[c * 52 + m], w2[m]);
        }
        const int rh7 = yr < 3 ? yr : (yr > 52 ? yr - 49 : 3);
        const int rw7 = xr < 3 ? xr : (xr > 52 ? xr - 49 : 3);
        #pragma unroll
        for (int i = 0; i < 7; ++i)
            #pragma unroll
            for (int j = 0; j < 7; ++j)
                w2[i * 7 + j] += rpb2_s[(rh7 + i) * 13 + (rw7 + j)];
        float mx = -1e30f;
        #pragma unroll
        for (int m = 0; m < 49; ++m) mx = fmaxf(mx, w2[m]);
        float sm = 0.f;
        #pragma unroll
        for (int m = 0; m < 49; ++m) { w2[m] = __expf(w2[m] - mx); sm += w2[m]; }
        const float r = 1.f / sm;
        #pragma unroll
        for (int m = 0; m < 49; ++m) w2[m] *= r;

        const float* vb = xb + (long)(32 + g * 8) * HW;
        float acc[8];
        #pragma unroll
        for (int ch = 0; ch < 8; ++ch) acc[ch] = 0.f;
        #pragma unroll
        for (int i = 0; i < 7; ++i) {
            const int y = ph + i - 3;
            if ((unsigned)y >= HH) continue;
            #pragma unroll
            for (int j = 0; j < 7; ++j) {
                const int xx = pw + j - 3;
                if ((unsigned)xx >= WW) continue;
                const int off = (i - 3) * WW + (j - 3);
                const float wv = w2[i * 7 + j];
                #pragma unroll
                for (int ch = 0; ch < 8; ++ch)
                    acc[ch] = fmaf(wv, vb[ch * HW + off], acc[ch]);
            }
        }
        float* m1 = mix + ((long)b * CC + 32 + g * 8) * HW + n;
        #pragma unroll
        for (int ch = 0; ch < 8; ++ch) m1[ch * HW] = acc[ch];
    }
}

// ---------------- final: 64x64 channel matmul + bn + lepe add ----------------
// 2 px (float2) x 16 outputs per thread; 4 wave-uniform output quarters per block.
// grid (25, B) = 800 blocks for occupancy.
__global__ __launch_bounds__(256) void final_k(const float* __restrict__ mix,
                                               const float* __restrict__ dy_w,
                                               const float* __restrict__ s,
                                               const float* __restrict__ bb,
                                               float* __restrict__ out) {
    __shared__ float w_s[64 * 64];      // transposed: w_s[i*64+o] = dy_w[o*64+i]
    const int tid = threadIdx.x;
    const int b = blockIdx.y;
    for (int i = tid; i < 4096; i += 256) w_s[(i & 63) * 64 + (i >> 6)] = dy_w[i];
    __syncthreads();
    const int ob = (tid >> 6) * 16;                 // wave-uniform output quarter
    const int p2 = blockIdx.x * 64 + (tid & 63);    // float2 pixel-pair index, HW/2=1568
    if (p2 >= 1568) return;
    const float2* mp = reinterpret_cast<const float2*>(mix + (long)b * CC * HW);
    float accx[16], accy[16];
    #pragma unroll
    for (int o = 0; o < 16; ++o) { accx[o] = 0.f; accy[o] = 0.f; }
    for (int i = 0; i < 64; ++i) {
        const float2 mv = mp[i * 1568 + p2];
        const float* wr = w_s + i * 64 + ob;
        #pragma unroll
        for (int o = 0; o < 16; ++o) {
            const float wv = wr[o];
            accx[o] = fmaf(wv, mv.x, accx[o]);
            accy[o] = fmaf(wv, mv.y, accy[o]);
        }
    }
    float2* op = reinterpret_cast<float2*>(out + (long)b * CC * HW);
    #pragma unroll
    for (int o = 0; o < 16; ++o) {
        const long idx = (long)(ob + o) * 1568 + p2;
        const float2 prev = op[idx];
        float2 res;
        res.x = fmaf(accx[o], s[ob + o], bb[ob + o]) + prev.x;
        res.y = fmaf(accy[o], s[ob + o], bb[ob + o]) + prev.y;
        op[idx] = res;
    }
}

extern "C" void kernel_launch(void* const* d_in, const int* in_sizes, int n_in,
                              void* d_out, int out_size, void* d_ws, size_t ws_size,
                              hipStream_t stream) {
    const float* x       = (const float*)d_in[0];
    const float* lepe_w  = (const float*)d_in[1];
    const float* lepe_b  = (const float*)d_in[2];
    const float* lepe_s  = (const float*)d_in[3];
    const float* lepe_bb = (const float*)d_in[4];
    const float* wq_w    = (const float*)d_in[5];
    const float* wq_s    = (const float*)d_in[6];
    const float* wq_bb   = (const float*)d_in[7];
    const float* wk_w    = (const float*)d_in[8];
    const float* wk_s    = (const float*)d_in[9];
    const float* wk_bb   = (const float*)d_in[10];
    const float* wp_w    = (const float*)d_in[11];
    const float* wp_b    = (const float*)d_in[12];
    const float* rpb1    = (const float*)d_in[13];
    const float* rpb2    = (const float*)d_in[14];
    const float* dy_w    = (const float*)d_in[15];
    const float* dy_s    = (const float*)d_in[16];
    const float* dy_bb   = (const float*)d_in[17];
    float* out = (float*)d_out;

    float* ws     = (float*)d_ws;
    float* WK_ws  = ws;                               // 128*640 = 81920
    float* mix_ws = WK_ws + 128 * 640;                // 32*64*3136 = 6422528

    const int nTiles = (HW + 255) / 256;              // 13

    lepe_k<<<dim3(4, BB * CC), 256, 0, stream>>>(x, lepe_w, lepe_b, lepe_s, lepe_bb, out);
    prep_k<<<dim3(BB * 4), 256, 0, stream>>>(x, wk_w, wk_s, wk_bb, wp_w, WK_ws);
    attnmix_k<<<dim3(nTiles, BB * 4), 256, 0, stream>>>(x, WK_ws, wq_w, wq_s, wq_bb,
                                                        wp_b, rpb1, rpb2, mix_ws);
    final_k<<<dim3(25, BB), 256, 0, stream>>>(mix_ws, dy_w, dy_s, dy_bb, out);
}

// Round 7
// 249.817 us; speedup vs baseline: 2.3460x; 1.0250x over previous
//
#include <hip/hip_runtime.h>

#define BB 32
#define CC 64
#define C2 32
#define HH 56
#define WW 56
#define HW 3136

// ---------------- lepe: depthwise 7x7 conv + bias + bn -> d_out ----------------
// grid (4, B*C): c block-uniform -> weight/bias reads are scalar (s_load, K$); no LDS.
__global__ __launch_bounds__(256) void lepe_k(const float* __restrict__ x,
                                              const float* __restrict__ wt,
                                              const float* __restrict__ b,
                                              const float* __restrict__ s,
                                              const float* __restrict__ bb,
                                              float* __restrict__ out) {
    const int bc = blockIdx.y;
    const int c = bc & 63;                              // block-uniform
    const int qi = blockIdx.x * 256 + threadIdx.x;      // pixel-quad index, need < 784
    if (qi >= 784) return;
    const int r = qi / 14;
    const int c4 = (qi % 14) * 4;
    const float* wp = wt + c * 49;                      // uniform base -> scalar loads
    const float* xp = x + (long)bc * HW;
    float acc0 = 0.f, acc1 = 0.f, acc2 = 0.f, acc3 = 0.f;
    #pragma unroll
    for (int i = 0; i < 7; ++i) {
        const int y = r + i - 3;
        if ((unsigned)y >= HH) continue;
        const float4* row = reinterpret_cast<const float4*>(xp + y * WW + c4 - 4);
        float4 A = make_float4(0.f, 0.f, 0.f, 0.f);
        float4 Cv = make_float4(0.f, 0.f, 0.f, 0.f);
        if (c4 != 0) A = row[0];
        const float4 Bv = row[1];
        if (c4 != 52) Cv = row[2];
        const float w12[12] = {A.x, A.y, A.z, A.w, Bv.x, Bv.y, Bv.z, Bv.w, Cv.x, Cv.y, Cv.z, Cv.w};
        #pragma unroll
        for (int j = 0; j < 7; ++j) {
            const float wv = wp[i * 7 + j];
            acc0 = fmaf(w12[j + 1], wv, acc0);
            acc1 = fmaf(w12[j + 2], wv, acc1);
            acc2 = fmaf(w12[j + 3], wv, acc2);
            acc3 = fmaf(w12[j + 4], wv, acc3);
        }
    }
    const float bc_ = b[c], sc = s[c], bbc = bb[c];
    float4 res;
    res.x = (acc0 + bc_) * sc + bbc;
    res.y = (acc1 + bc_) * sc + bbc;
    res.z = (acc2 + bc_) * sc + bbc;
    res.w = (acc3 + bc_) * sc + bbc;
    *reinterpret_cast<float4*>(out + (long)bc * HW + r * WW + c4) = res;
}

// ---------------- prep: pool(8x8 mean) -> wk matmul+bn -> WK = wp * kg^T ----------------
// One block per (b,g). Output per bg: WK1[c][28] (25 used) then WK2[c][52] (49 used), 640 floats.
__global__ __launch_bounds__(256) void prep_k(const float* __restrict__ x,
                                              const float* __restrict__ wk,
                                              const float* __restrict__ wks,
                                              const float* __restrict__ wkb,
                                              const float* __restrict__ wp_w,
                                              float* __restrict__ WK) {
    __shared__ float p_s[32 * 49];
    __shared__ float kg_s[8 * 49];
    const int b = blockIdx.x >> 2;
    const int g = blockIdx.x & 3;
    const int tid = threadIdx.x;
    for (int idx = tid; idx < 1568; idx += 256) {
        const int i = idx / 49, l = idx % 49;
        const int py = l / 7, px = l % 7;
        const float4* xp4 = reinterpret_cast<const float4*>(
            x + ((long)(b * CC + 32 + i)) * HW + py * 8 * WW + px * 8);
        float4 sA = make_float4(0.f, 0.f, 0.f, 0.f);
        float4 sB = make_float4(0.f, 0.f, 0.f, 0.f);
        #pragma unroll
        for (int y = 0; y < 8; ++y) {
            const float4 a = xp4[y * 14];
            const float4 c = xp4[y * 14 + 1];
            sA.x += a.x; sA.y += a.y; sA.z += a.z; sA.w += a.w;
            sB.x += c.x; sB.y += c.y; sB.z += c.z; sB.w += c.w;
        }
        p_s[idx] = (sA.x + sA.y + sA.z + sA.w + sB.x + sB.y + sB.z + sB.w) * (1.f / 64.f);
    }
    __syncthreads();
    for (int idx = tid; idx < 392; idx += 256) {       // 8 outputs of this group x 49
        const int o8 = idx / 49, l = idx % 49;
        const int o = g * 8 + o8;
        float acc = 0.f;
        #pragma unroll
        for (int i = 0; i < 32; ++i) acc = fmaf(wk[o * 32 + i], p_s[i * 49 + l], acc);
        kg_s[idx] = acc * wks[o] + wkb[o];
    }
    __syncthreads();
    for (int idx = tid; idx < 640; idx += 256) {       // 8 c x 80 slots
        const int c = idx / 80, slot = idx % 80;
        float acc = 0.f;
        int m = -1;
        if (slot < 28) { if (slot < 25) m = slot; }
        else           { if (slot < 77) m = 25 + (slot - 28); }
        if (m >= 0) {
            const float* kp = kg_s + c * 49;
            #pragma unroll
            for (int l = 0; l < 49; ++l) acc = fmaf(wp_w[m * 49 + l], kp[l], acc);
        }
        const long base = (long)blockIdx.x * 640;
        if (slot < 28) WK[base + c * 28 + slot] = acc;
        else           WK[base + 224 + c * 52 + (slot - 28)] = acc;
    }
}

// ---------------- fused q-proj + attention (wm via WK -> +rpb -> softmax) + dyn_mix ----------------
// Per (b,g) block. q8 computed inline (no q workspace). Two phases, 8-acc ILP gathers.
__global__ __launch_bounds__(256) void attnmix_k(const float* __restrict__ x,
                                                 const float* __restrict__ WK,
                                                 const float* __restrict__ wq_w,
                                                 const float* __restrict__ wq_s,
                                                 const float* __restrict__ wq_bb,
                                                 const float* __restrict__ wp_b,
                                                 const float* __restrict__ rpb1,
                                                 const float* __restrict__ rpb2,
                                                 float* __restrict__ mix) {
    __shared__ float WK1_s[8 * 28];     // [c][28], pad zeroed
    __shared__ float WK2_s[8 * 52];     // [c][52], pad zeroed
    __shared__ float wqT_s[32 * 8];     // [i][c] = wq_w[(g*8+c)*32+i]
    __shared__ float wpb1_s[25];
    __shared__ float wpb2_s[49];
    __shared__ float rpb1_s[81];
    __shared__ float rpb2_s[169];
    __shared__ float wqbn_s[16];        // [0..7]=s, [8..15]=b
    const int tid = threadIdx.x;
    const int bg = blockIdx.y;
    const int g = bg & 3, b = bg >> 2;
    {
        const float* wkp = WK + (long)bg * 640;
        for (int i = tid; i < 224; i += 256) WK1_s[i] = wkp[i];
        for (int i = tid; i < 416; i += 256) WK2_s[i] = wkp[224 + i];
    }
    if (tid < 256) {                    // wqT: i = tid>>3, c = tid&7
        const int i = tid >> 3, c = tid & 7;
        wqT_s[tid] = wq_w[(g * 8 + c) * 32 + i];
    }
    if (tid < 25) wpb1_s[tid] = wp_b[tid];
    if (tid >= 32 && tid < 81) wpb2_s[tid - 32] = wp_b[25 + tid - 32];
    if (tid < 81) rpb1_s[tid] = rpb1[g * 81 + tid];
    if (tid < 169) rpb2_s[tid] = rpb2[g * 169 + tid];
    if (tid >= 192 && tid < 200) wqbn_s[tid - 192] = wq_s[g * 8 + tid - 192];
    if (tid >= 200 && tid < 208) wqbn_s[8 + tid - 200] = wq_bb[g * 8 + tid - 200];
    __syncthreads();
    const int n = blockIdx.x * 256 + tid;
    if (n >= HW) return;

    const int ph = n / WW, pw = n % WW;
    const int yr = HH - 1 - ph, xr = WW - 1 - pw;

    const float* xb = x + (long)b * CC * HW + n;       // pixel-n base, channel stride HW

    // ---- q8 inline: q = wq . x[0..32) , bn, *SCALE ----
    float q8[8];
    #pragma unroll
    for (int c = 0; c < 8; ++c) q8[c] = 0.f;
    for (int i = 0; i < 32; ++i) {
        const float xv = xb[i * HW];
        #pragma unroll
        for (int c = 0; c < 8; ++c) q8[c] = fmaf(wqT_s[i * 8 + c], xv, q8[c]);
    }
    #pragma unroll
    for (int c = 0; c < 8; ++c)
        q8[c] = (q8[c] * wqbn_s[c] + wqbn_s[8 + c]) * 0.25f;

    __builtin_amdgcn_sched_barrier(0);

    // ======== phase 1: 25 weights, 5x5 mix over v0 ========
    {
        float w1[25];
        #pragma unroll
        for (int m = 0; m < 25; ++m) w1[m] = wpb1_s[m];
        #pragma unroll
        for (int c = 0; c < 8; ++c) {
            const float qv = q8[c];
            #pragma unroll
            for (int m = 0; m < 25; ++m) w1[m] = fmaf(qv, WK1_s[c * 28 + m], w1[m]);
        }
        const int rh5 = yr < 2 ? yr : (yr > 53 ? yr - 51 : 2);
        const int rw5 = xr < 2 ? xr : (xr > 53 ? xr - 51 : 2);
        #pragma unroll
        for (int i = 0; i < 5; ++i)
            #pragma unroll
            for (int j = 0; j < 5; ++j)
                w1[i * 5 + j] += rpb1_s[(rh5 + i) * 9 + (rw5 + j)];
        float mx = -1e30f;
        #pragma unroll
        for (int m = 0; m < 25; ++m) mx = fmaxf(mx, w1[m]);
        float sm = 0.f;
        #pragma unroll
        for (int m = 0; m < 25; ++m) { w1[m] = __expf(w1[m] - mx); sm += w1[m]; }
        const float r = 1.f / sm;
        #pragma unroll
        for (int m = 0; m < 25; ++m) w1[m] *= r;

        const float* vb = xb + (long)(g * 8) * HW;
        float acc[8];
        #pragma unroll
        for (int ch = 0; ch < 8; ++ch) acc[ch] = 0.f;
        #pragma unroll
        for (int i = 0; i < 5; ++i) {
            const int y = ph + i - 2;
            if ((unsigned)y >= HH) continue;
            #pragma unroll
            for (int j = 0; j < 5; ++j) {
                const int xx = pw + j - 2;
                if ((unsigned)xx >= WW) continue;
                const int off = (i - 2) * WW + (j - 2);
                const float wv = w1[i * 5 + j];
                #pragma unroll
                for (int ch = 0; ch < 8; ++ch)
                    acc[ch] = fmaf(wv, vb[ch * HW + off], acc[ch]);
            }
        }
        float* m0 = mix + ((long)b * CC + g * 8) * HW + n;
        #pragma unroll
        for (int ch = 0; ch < 8; ++ch) m0[ch * HW] = acc[ch];
    }

    __builtin_amdgcn_sched_barrier(0);   // keep phases from merging (register pressure)

    // ======== phase 2: 49 weights, 7x7 mix over v1 ========
    {
        float w2[49];
        #pragma unroll
        for (int m = 0; m < 49; ++m) w2[m] = wpb2_s[m];
        #pragma unroll
        for (int c = 0; c < 8; ++c) {
            const float qv = q8[c];
            #pragma unroll
            for (int m = 0; m < 49; ++m) w2[m] = fmaf(qv, WK2_s[c * 52 + m], w2[m]);
        }
        const int rh7 = yr < 3 ? yr : (yr > 52 ? yr - 49 : 3);
        const int rw7 = xr < 3 ? xr : (xr > 52 ? xr - 49 : 3);
        #pragma unroll
        for (int i = 0; i < 7; ++i)
            #pragma unroll
            for (int j = 0; j < 7; ++j)
                w2[i * 7 + j] += rpb2_s[(rh7 + i) * 13 + (rw7 + j)];
        float mx = -1e30f;
        #pragma unroll
        for (int m = 0; m < 49; ++m) mx = fmaxf(mx, w2[m]);
        float sm = 0.f;
        #pragma unroll
        for (int m = 0; m < 49; ++m) { w2[m] = __expf(w2[m] - mx); sm += w2[m]; }
        const float r = 1.f / sm;
        #pragma unroll
        for (int m = 0; m < 49; ++m) w2[m] *= r;

        const float* vb = xb + (long)(32 + g * 8) * HW;
        float acc[8];
        #pragma unroll
        for (int ch = 0; ch < 8; ++ch) acc[ch] = 0.f;
        #pragma unroll
        for (int i = 0; i < 7; ++i) {
            const int y = ph + i - 3;
            if ((unsigned)y >= HH) continue;
            #pragma unroll
            for (int j = 0; j < 7; ++j) {
                const int xx = pw + j - 3;
                if ((unsigned)xx >= WW) continue;
                const int off = (i - 3) * WW + (j - 3);
                const float wv = w2[i * 7 + j];
                #pragma unroll
                for (int ch = 0; ch < 8; ++ch)
                    acc[ch] = fmaf(wv, vb[ch * HW + off], acc[ch]);
            }
        }
        float* m1 = mix + ((long)b * CC + 32 + g * 8) * HW + n;
        #pragma unroll
        for (int ch = 0; ch < 8; ++ch) m1[ch * HW] = acc[ch];
    }
}

// ---------------- final: 64x64 channel matmul + bn + lepe add ----------------
// Thread = 4 px (float4) x 8 outs. Per i: 2 b128 LDS (2-way aliased, free) + 1 float4 load + 32 FMA.
// grid (25, B): block covers 128 px x 64 outs.
__global__ __launch_bounds__(256) void final_k(const float* __restrict__ mix,
                                               const float* __restrict__ dy_w,
                                               const float* __restrict__ s,
                                               const float* __restrict__ bb,
                                               float* __restrict__ out) {
    __shared__ float w_s[64 * 64];      // transposed: w_s[i*64+o] = dy_w[o*64+i]
    const int tid = threadIdx.x;
    const int b = blockIdx.y;
    for (int i = tid; i < 4096; i += 256) w_s[(i & 63) * 64 + (i >> 6)] = dy_w[i];
    __syncthreads();
    const int oo = (tid >> 5) * 8;                  // output octant base (half-wave uniform)
    const int p4 = blockIdx.x * 32 + (tid & 31);    // float4 pixel group, need < 784
    if (p4 >= 784) return;
    const float* mp = mix + (long)b * CC * HW + p4 * 4;
    float4 acc[8];
    #pragma unroll
    for (int o = 0; o < 8; ++o) acc[o] = make_float4(0.f, 0.f, 0.f, 0.f);
    for (int i = 0; i < 64; ++i) {
        const float4 mv = *reinterpret_cast<const float4*>(mp + (long)i * HW);
        const float* wr = w_s + i * 64 + oo;
        #pragma unroll
        for (int o = 0; o < 8; ++o) {
            const float wv = wr[o];
            acc[o].x = fmaf(wv, mv.x, acc[o].x);
            acc[o].y = fmaf(wv, mv.y, acc[o].y);
            acc[o].z = fmaf(wv, mv.z, acc[o].z);
            acc[o].w = fmaf(wv, mv.w, acc[o].w);
        }
    }
    float* op = out + (long)b * CC * HW + p4 * 4;
    #pragma unroll
    for (int o = 0; o < 8; ++o) {
        const float sc = s[oo + o], bc = bb[oo + o];
        float4* dst = reinterpret_cast<float4*>(op + (long)(oo + o) * HW);
        float4 prev = *dst;
        prev.x = fmaf(acc[o].x, sc, bc) + prev.x;
        prev.y = fmaf(acc[o].y, sc, bc) + prev.y;
        prev.z = fmaf(acc[o].z, sc, bc) + prev.z;
        prev.w = fmaf(acc[o].w, sc, bc) + prev.w;
        *dst = prev;
    }
}

extern "C" void kernel_launch(void* const* d_in, const int* in_sizes, int n_in,
                              void* d_out, int out_size, void* d_ws, size_t ws_size,
                              hipStream_t stream) {
    const float* x       = (const float*)d_in[0];
    const float* lepe_w  = (const float*)d_in[1];
    const float* lepe_b  = (const float*)d_in[2];
    const float* lepe_s  = (const float*)d_in[3];
    const float* lepe_bb = (const float*)d_in[4];
    const float* wq_w    = (const float*)d_in[5];
    const float* wq_s    = (const float*)d_in[6];
    const float* wq_bb   = (const float*)d_in[7];
    const float* wk_w    = (const float*)d_in[8];
    const float* wk_s    = (const float*)d_in[9];
    const float* wk_bb   = (const float*)d_in[10];
    const float* wp_w    = (const float*)d_in[11];
    const float* wp_b    = (const float*)d_in[12];
    const float* rpb1    = (const float*)d_in[13];
    const float* rpb2    = (const float*)d_in[14];
    const float* dy_w    = (const float*)d_in[15];
    const float* dy_s    = (const float*)d_in[16];
    const float* dy_bb   = (const float*)d_in[17];
    float* out = (float*)d_out;

    float* ws     = (float*)d_ws;
    float* WK_ws  = ws;                               // 128*640 = 81920
    float* mix_ws = WK_ws + 128 * 640;                // 32*64*3136 = 6422528

    const int nTiles = (HW + 255) / 256;              // 13

    lepe_k<<<dim3(4, BB * CC), 256, 0, stream>>>(x, lepe_w, lepe_b, lepe_s, lepe_bb, out);
    prep_k<<<dim3(BB * 4), 256, 0, stream>>>(x, wk_w, wk_s, wk_bb, wp_w, WK_ws);
    attnmix_k<<<dim3(nTiles, BB * 4), 256, 0, stream>>>(x, WK_ws, wq_w, wq_s, wq_bb,
                                                        wp_b, rpb1, rpb2, mix_ws);
    final_k<<<dim3(25, BB), 256, 0, stream>>>(mix_ws, dy_w, dy_s, dy_bb, out);
}

// Round 8
// 243.512 us; speedup vs baseline: 2.4067x; 1.0259x over previous
//
#include <hip/hip_runtime.h>

#define BB 32
#define CC 64
#define HH 56
#define WW 56
#define HW 3136
#define TW 64
#define TR 12

// ---------------- prep: pool(8x8 mean) -> wk matmul+bn -> WK = wp * kg^T ----------------
__global__ __launch_bounds__(256) void prep_k(const float* __restrict__ x,
                                              const float* __restrict__ wk,
                                              const float* __restrict__ wks,
                                              const float* __restrict__ wkb,
                                              const float* __restrict__ wp_w,
                                              float* __restrict__ WK) {
    __shared__ float p_s[32 * 49];
    __shared__ float kg_s[8 * 49];
    const int b = blockIdx.x >> 2;
    const int g = blockIdx.x & 3;
    const int tid = threadIdx.x;
    for (int idx = tid; idx < 1568; idx += 256) {
        const int i = idx / 49, l = idx % 49;
        const int py = l / 7, px = l % 7;
        const float4* xp4 = reinterpret_cast<const float4*>(
            x + ((long)(b * CC + 32 + i)) * HW + py * 8 * WW + px * 8);
        float4 sA = make_float4(0.f, 0.f, 0.f, 0.f);
        float4 sB = make_float4(0.f, 0.f, 0.f, 0.f);
        #pragma unroll
        for (int y = 0; y < 8; ++y) {
            const float4 a = xp4[y * 14];
            const float4 c = xp4[y * 14 + 1];
            sA.x += a.x; sA.y += a.y; sA.z += a.z; sA.w += a.w;
            sB.x += c.x; sB.y += c.y; sB.z += c.z; sB.w += c.w;
        }
        p_s[idx] = (sA.x + sA.y + sA.z + sA.w + sB.x + sB.y + sB.z + sB.w) * (1.f / 64.f);
    }
    __syncthreads();
    for (int idx = tid; idx < 392; idx += 256) {
        const int o8 = idx / 49, l = idx % 49;
        const int o = g * 8 + o8;
        float acc = 0.f;
        #pragma unroll
        for (int i = 0; i < 32; ++i) acc = fmaf(wk[o * 32 + i], p_s[i * 49 + l], acc);
        kg_s[idx] = acc * wks[o] + wkb[o];
    }
    __syncthreads();
    for (int idx = tid; idx < 640; idx += 256) {
        const int c = idx / 80, slot = idx % 80;
        float acc = 0.f;
        int m = -1;
        if (slot < 28) { if (slot < 25) m = slot; }
        else           { if (slot < 77) m = 25 + (slot - 28); }
        if (m >= 0) {
            const float* kp = kg_s + c * 49;
            #pragma unroll
            for (int l = 0; l < 49; ++l) acc = fmaf(wp_w[m * 49 + l], kp[l], acc);
        }
        const long base = (long)blockIdx.x * 640;
        if (slot < 28) WK[base + c * 28 + slot] = acc;
        else           WK[base + 224 + c * 52 + (slot - 28)] = acc;
    }
}

// ---------------- fused q-proj + attention + dyn_mix + lepe ----------------
// Per (b,g) block. x-tile (8ch x 12rows x 64cols, zero-padded halo) staged in LDS per phase.
// The 49 tile reads per channel feed BOTH the attention gather and the lepe 7x7 conv.
__global__ __launch_bounds__(256) void attnmix_k(const float* __restrict__ x,
                                                 const float* __restrict__ WK,
                                                 const float* __restrict__ wq_w,
                                                 const float* __restrict__ wq_s,
                                                 const float* __restrict__ wq_bb,
                                                 const float* __restrict__ wp_b,
                                                 const float* __restrict__ rpb1,
                                                 const float* __restrict__ rpb2,
                                                 const float* __restrict__ lw,
                                                 const float* __restrict__ lb,
                                                 const float* __restrict__ ls,
                                                 const float* __restrict__ lbb,
                                                 float* __restrict__ mix,
                                                 float* __restrict__ out) {
    __shared__ float tile[8 * TR * TW];   // 24 KB
    __shared__ float WK1_s[8 * 28];
    __shared__ float WK2_s[8 * 52];
    __shared__ float wqT_s[32 * 8];
    __shared__ float wpb1_s[25];
    __shared__ float wpb2_s[49];
    __shared__ float rpb1_s[81];
    __shared__ float rpb2_s[169];
    __shared__ float wqbn_s[16];
    __shared__ float lw_s[16 * 49];       // lepe weights for the 16 channels of this (g)
    __shared__ float lbn_s[48];           // [0..15]=b, [16..31]=s, [32..47]=bb
    const int tid = threadIdx.x;
    const int bg = blockIdx.y;
    const int g = bg & 3, b = bg >> 2;

    {
        const float* wkp = WK + (long)bg * 640;
        for (int i = tid; i < 224; i += 256) WK1_s[i] = wkp[i];
        for (int i = tid; i < 416; i += 256) WK2_s[i] = wkp[224 + i];
    }
    {
        const int i = tid >> 3, c = tid & 7;
        wqT_s[tid] = wq_w[(g * 8 + c) * 32 + i];
    }
    if (tid < 25) wpb1_s[tid] = wp_b[tid];
    if (tid >= 32 && tid < 81) wpb2_s[tid - 32] = wp_b[25 + tid - 32];
    if (tid < 81) rpb1_s[tid] = rpb1[g * 81 + tid];
    if (tid < 169) rpb2_s[tid] = rpb2[g * 169 + tid];
    if (tid >= 192 && tid < 200) wqbn_s[tid - 192] = wq_s[g * 8 + tid - 192];
    if (tid >= 200 && tid < 208) wqbn_s[8 + tid - 200] = wq_bb[g * 8 + tid - 200];
    for (int i = tid; i < 784; i += 256) {
        const int ch = i / 49, k = i % 49;
        const int c = (ch < 8) ? (g * 8 + ch) : (32 + g * 8 + ch - 8);
        lw_s[i] = lw[c * 49 + k];
    }
    if (tid < 16) {
        const int c = (tid < 8) ? (g * 8 + tid) : (32 + g * 8 + tid - 8);
        lbn_s[tid] = lb[c]; lbn_s[16 + tid] = ls[c]; lbn_s[32 + tid] = lbb[c];
    }

    const int N0 = blockIdx.x << 8;
    const int ph0 = N0 / WW;             // block-uniform
    const int r0 = ph0 - 3;

    // ---- stage v0 tile (channels g*8 .. g*8+8) ----
    {
        const float* xc = x + ((long)b * CC + g * 8) * HW;
        #pragma unroll
        for (int ch = 0; ch < 8; ++ch)
            for (int k = tid; k < TR * TW; k += 256) {
                const int row = k >> 6, lxx = k & 63;
                const int gy = r0 + row, gx = lxx - 3;
                float v = 0.f;
                if ((unsigned)gy < HH && (unsigned)gx < WW) v = xc[ch * HW + gy * WW + gx];
                tile[ch * (TR * TW) + k] = v;
            }
    }
    __syncthreads();

    const int n = N0 + tid;
    const bool valid = n < HW;
    const int nc = valid ? n : HW - 1;
    const int ph = nc / WW, pw = nc % WW;
    const int yr = HH - 1 - ph, xr = WW - 1 - pw;
    const int lrow = ph - r0;            // in [3, 8]
    const int tb0 = (lrow - 3) * TW + pw;   // tile offset of tap (i=0,j=0) = (ph-3, pw-3)

    const float* xb = x + (long)b * CC * HW + nc;

    // ---- q8: q = wq . x[0..32), bn, *SCALE ----
    float q8[8];
    #pragma unroll
    for (int c = 0; c < 8; ++c) q8[c] = 0.f;
    for (int i = 0; i < 32; ++i) {
        const float xv = xb[i * HW];
        #pragma unroll
        for (int c = 0; c < 8; ++c) q8[c] = fmaf(wqT_s[i * 8 + c], xv, q8[c]);
    }
    #pragma unroll
    for (int c = 0; c < 8; ++c)
        q8[c] = (q8[c] * wqbn_s[c] + wqbn_s[8 + c]) * 0.25f;

    __builtin_amdgcn_sched_barrier(0);

    // ======== phase 1: 25-weight softmax, 5x5 gather + lepe 7x7 over v0 ========
    {
        float w1[25];
        #pragma unroll
        for (int m = 0; m < 25; ++m) w1[m] = wpb1_s[m];
        #pragma unroll
        for (int c = 0; c < 8; ++c) {
            const float qv = q8[c];
            #pragma unroll
            for (int m = 0; m < 25; ++m) w1[m] = fmaf(qv, WK1_s[c * 28 + m], w1[m]);
        }
        const int rh5 = yr < 2 ? yr : (yr > 53 ? yr - 51 : 2);
        const int rw5 = xr < 2 ? xr : (xr > 53 ? xr - 51 : 2);
        #pragma unroll
        for (int i = 0; i < 5; ++i)
            #pragma unroll
            for (int j = 0; j < 5; ++j)
                w1[i * 5 + j] += rpb1_s[(rh5 + i) * 9 + (rw5 + j)];
        float mx = -1e30f;
        #pragma unroll
        for (int m = 0; m < 25; ++m) mx = fmaxf(mx, w1[m]);
        float sm = 0.f;
        #pragma unroll
        for (int m = 0; m < 25; ++m) { w1[m] = __expf(w1[m] - mx); sm += w1[m]; }
        const float r = 1.f / sm;
        #pragma unroll
        for (int m = 0; m < 25; ++m) w1[m] *= r;

        float* m0 = mix + ((long)b * CC + g * 8) * HW + nc;
        float* o0 = out + ((long)b * CC + g * 8) * HW + nc;
        #pragma unroll
        for (int ch = 0; ch < 8; ++ch) {
            const float* t = tile + ch * (TR * TW) + tb0;
            const float* lwc = lw_s + ch * 49;
            float a = 0.f, la = 0.f;
            #pragma unroll
            for (int i = 0; i < 7; ++i)
                #pragma unroll
                for (int j = 0; j < 7; ++j) {
                    const float v = t[i * TW + j];
                    la = fmaf(lwc[i * 7 + j], v, la);
                    if (i >= 1 && i <= 5 && j >= 1 && j <= 5)
                        a = fmaf(w1[(i - 1) * 5 + (j - 1)], v, a);
                }
            if (valid) {
                m0[ch * HW] = a;
                o0[ch * HW] = (la + lbn_s[ch]) * lbn_s[16 + ch] + lbn_s[32 + ch];
            }
        }
    }

    __syncthreads();                      // tile reads done
    // ---- re-stage tile with v1 channels (32 + g*8 ..) ----
    {
        const float* xc = x + ((long)b * CC + 32 + g * 8) * HW;
        #pragma unroll
        for (int ch = 0; ch < 8; ++ch)
            for (int k = tid; k < TR * TW; k += 256) {
                const int row = k >> 6, lxx = k & 63;
                const int gy = r0 + row, gx = lxx - 3;
                float v = 0.f;
                if ((unsigned)gy < HH && (unsigned)gx < WW) v = xc[ch * HW + gy * WW + gx];
                tile[ch * (TR * TW) + k] = v;
            }
    }
    __syncthreads();

    // ======== phase 2: 49-weight softmax, 7x7 gather + lepe 7x7 over v1 ========
    {
        float w2[49];
        #pragma unroll
        for (int m = 0; m < 49; ++m) w2[m] = wpb2_s[m];
        #pragma unroll
        for (int c = 0; c < 8; ++c) {
            const float qv = q8[c];
            #pragma unroll
            for (int m = 0; m < 49; ++m) w2[m] = fmaf(qv, WK2_s[c * 52 + m], w2[m]);
        }
        const int rh7 = yr < 3 ? yr : (yr > 52 ? yr - 49 : 3);
        const int rw7 = xr < 3 ? xr : (xr > 52 ? xr - 49 : 3);
        #pragma unroll
        for (int i = 0; i < 7; ++i)
            #pragma unroll
            for (int j = 0; j < 7; ++j)
                w2[i * 7 + j] += rpb2_s[(rh7 + i) * 13 + (rw7 + j)];
        float mx = -1e30f;
        #pragma unroll
        for (int m = 0; m < 49; ++m) mx = fmaxf(mx, w2[m]);
        float sm = 0.f;
        #pragma unroll
        for (int m = 0; m < 49; ++m) { w2[m] = __expf(w2[m] - mx); sm += w2[m]; }
        const float r = 1.f / sm;
        #pragma unroll
        for (int m = 0; m < 49; ++m) w2[m] *= r;

        float* m1 = mix + ((long)b * CC + 32 + g * 8) * HW + nc;
        float* o1 = out + ((long)b * CC + 32 + g * 8) * HW + nc;
        #pragma unroll
        for (int ch = 0; ch < 8; ++ch) {
            const float* t = tile + ch * (TR * TW) + tb0;
            const float* lwc = lw_s + (8 + ch) * 49;
            float a = 0.f, la = 0.f;
            #pragma unroll
            for (int i = 0; i < 7; ++i)
                #pragma unroll
                for (int j = 0; j < 7; ++j) {
                    const float v = t[i * TW + j];
                    la = fmaf(lwc[i * 7 + j], v, la);
                    a = fmaf(w2[i * 7 + j], v, a);
                }
            if (valid) {
                m1[ch * HW] = a;
                o1[ch * HW] = (la + lbn_s[8 + ch]) * lbn_s[16 + 8 + ch] + lbn_s[32 + 8 + ch];
            }
        }
    }
}

// ---------------- final: 64x64 channel matmul + bn + lepe add ----------------
__global__ __launch_bounds__(256) void final_k(const float* __restrict__ mix,
                                               const float* __restrict__ dy_w,
                                               const float* __restrict__ s,
                                               const float* __restrict__ bb,
                                               float* __restrict__ out) {
    __shared__ float w_s[64 * 64];      // transposed: w_s[i*64+o] = dy_w[o*64+i]
    const int tid = threadIdx.x;
    const int b = blockIdx.y;
    for (int i = tid; i < 4096; i += 256) w_s[(i & 63) * 64 + (i >> 6)] = dy_w[i];
    __syncthreads();
    const int oo = (tid >> 5) * 8;                  // output octant base
    const int p4 = blockIdx.x * 32 + (tid & 31);    // float4 pixel group, need < 784
    if (p4 >= 784) return;
    const float* mp = mix + (long)b * CC * HW + p4 * 4;
    float4 acc[8];
    #pragma unroll
    for (int o = 0; o < 8; ++o) acc[o] = make_float4(0.f, 0.f, 0.f, 0.f);
    for (int i = 0; i < 64; ++i) {
        const float4 mv = *reinterpret_cast<const float4*>(mp + (long)i * HW);
        const float* wr = w_s + i * 64 + oo;
        #pragma unroll
        for (int o = 0; o < 8; ++o) {
            const float wv = wr[o];
            acc[o].x = fmaf(wv, mv.x, acc[o].x);
            acc[o].y = fmaf(wv, mv.y, acc[o].y);
            acc[o].z = fmaf(wv, mv.z, acc[o].z);
            acc[o].w = fmaf(wv, mv.w, acc[o].w);
        }
    }
    float* op = out + (long)b * CC * HW + p4 * 4;
    #pragma unroll
    for (int o = 0; o < 8; ++o) {
        const float sc = s[oo + o], bc = bb[oo + o];
        float4* dst = reinterpret_cast<float4*>(op + (long)(oo + o) * HW);
        float4 prev = *dst;
        prev.x = fmaf(acc[o].x, sc, bc) + prev.x;
        prev.y = fmaf(acc[o].y, sc, bc) + prev.y;
        prev.z = fmaf(acc[o].z, sc, bc) + prev.z;
        prev.w = fmaf(acc[o].w, sc, bc) + prev.w;
        *dst = prev;
    }
}

extern "C" void kernel_launch(void* const* d_in, const int* in_sizes, int n_in,
                              void* d_out, int out_size, void* d_ws, size_t ws_size,
                              hipStream_t stream) {
    const float* x       = (const float*)d_in[0];
    const float* lepe_w  = (const float*)d_in[1];
    const float* lepe_b  = (const float*)d_in[2];
    const float* lepe_s  = (const float*)d_in[3];
    const float* lepe_bb = (const float*)d_in[4];
    const float* wq_w    = (const float*)d_in[5];
    const float* wq_s    = (const float*)d_in[6];
    const float* wq_bb   = (const float*)d_in[7];
    const float* wk_w    = (const float*)d_in[8];
    const float* wk_s    = (const float*)d_in[9];
    const float* wk_bb   = (const float*)d_in[10];
    const float* wp_w    = (const float*)d_in[11];
    const float* wp_b    = (const float*)d_in[12];
    const float* rpb1    = (const float*)d_in[13];
    const float* rpb2    = (const float*)d_in[14];
    const float* dy_w    = (const float*)d_in[15];
    const float* dy_s    = (const float*)d_in[16];
    const float* dy_bb   = (const float*)d_in[17];
    float* out = (float*)d_out;

    float* ws     = (float*)d_ws;
    float* WK_ws  = ws;                               // 128*640 = 81920
    float* mix_ws = WK_ws + 128 * 640;                // 32*64*3136 = 6422528

    const int nTiles = (HW + 255) / 256;              // 13

    prep_k<<<dim3(BB * 4), 256, 0, stream>>>(x, wk_w, wk_s, wk_bb, wp_w, WK_ws);
    attnmix_k<<<dim3(nTiles, BB * 4), 256, 0, stream>>>(x, WK_ws, wq_w, wq_s, wq_bb,
                                                        wp_b, rpb1, rpb2,
                                                        lepe_w, lepe_b, lepe_s, lepe_bb,
                                                        mix_ws, out);
    final_k<<<dim3(25, BB), 256, 0, stream>>>(mix_ws, dy_w, dy_s, dy_bb, out);
}